// Round 11
// baseline (227.281 us; speedup 1.0000x reference)
//
#include <hip/hip_runtime.h>
#include <hip/hip_bf16.h>

#define SENTINEL 24635

typedef unsigned char f8_t;  // OCP e4m3 storage
using bf16x8  = __attribute__((ext_vector_type(8))) __bf16;
using bf16x2  = __attribute__((ext_vector_type(2))) __bf16;
using floatx4 = __attribute__((ext_vector_type(4))) float;

__device__ inline bf16x8 cvt8(float4 a, float4 b) {
  bf16x8 v;
  v[0] = (__bf16)a.x; v[1] = (__bf16)a.y; v[2] = (__bf16)a.z; v[3] = (__bf16)a.w;
  v[4] = (__bf16)b.x; v[5] = (__bf16)b.y; v[6] = (__bf16)b.z; v[7] = (__bf16)b.w;
  return v;
}

__device__ inline int pack4_fp8(float4 a, float s) {
  int w = __builtin_amdgcn_cvt_pk_fp8_f32(a.x * s, a.y * s, 0, false);
  return __builtin_amdgcn_cvt_pk_fp8_f32(a.z * s, a.w * s, w, true);
}

// pack 8 scaled floats -> 8 e4m3 bytes
__device__ inline void store_fp8x8(f8_t* d, float4 a, float4 b, float s) {
  int2 v; v.x = pack4_fp8(a, s); v.y = pack4_fp8(b, s);
  *(int2*)d = v;
}

// async global->LDS, 16 B per lane. LDS dest = wave-uniform base + lane*16.
__device__ inline void gll16(const void* g, void* l) {
  __builtin_amdgcn_global_load_lds(
      (const __attribute__((address_space(1))) unsigned int*)g,
      (__attribute__((address_space(3))) unsigned int*)l, 16, 0, 0);
}

// ---------------------------------------------------------------------------
// Prep: f32->fp8 convert of W1/W2/W3 (x16, epilogue undoes; blocks 0..607)
// fused with pool (blocks 608..1631): user_n[b] = bf16 masked mean of
// ent_embs[ent_list[b,:cnt]]; cnt = first-SENTINEL prefix; cnt==0 -> sentinel.
// ---------------------------------------------------------------------------
__global__ __launch_bounds__(256) void prep_kernel(
    const float* __restrict__ s1, f8_t* __restrict__ d1,
    const float* __restrict__ s2, f8_t* __restrict__ d2,
    const float* __restrict__ s3, f8_t* __restrict__ d3,
    const float* __restrict__ ent, const int* __restrict__ ent_list,
    __bf16* __restrict__ user_n) {
  if (blockIdx.x < 608) {
    // sizes in 8-elem units: W1 98304, W2 49152, W3 8192
    int g = blockIdx.x * 256 + threadIdx.x;
    const float* s; f8_t* d; int i;
    if (g < 98304)       { s = s1; d = d1; i = g; }
    else if (g < 147456) { s = s2; d = d2; i = g - 98304; }
    else if (g < 155648) { s = s3; d = d3; i = g - 147456; }
    else return;
    i *= 8;
    float4 a = *(const float4*)(s + i);
    float4 b = *(const float4*)(s + i + 4);
    store_fp8x8(d + i, a, b, 16.f);
    return;
  }
  const int b = (blockIdx.x - 608) * 4 + (threadIdx.x >> 6);
  const int lane = threadIdx.x & 63;
  int myidx = (lane < 50) ? ent_list[b * 50 + lane] : 0;
  unsigned long long m = __ballot(lane < 50 && myidx == SENTINEL);
  const int cnt = (m == 0) ? 50 : (int)__builtin_ctzll(m);

  float sx = 0.f, sy = 0.f;
  for (int l0 = 0; l0 < 50; l0 += 10) {
    if (l0 >= cnt) break;  // wave-uniform
    float2 e[10];
#pragma unroll
    for (int j = 0; j < 10; ++j) {
      int idx = __shfl(myidx, l0 + j);
      e[j] = *(const float2*)(ent + (size_t)idx * 128 + lane * 2);
    }
#pragma unroll
    for (int j = 0; j < 10; ++j) {
      if (l0 + j < cnt) { sx += e[j].x; sy += e[j].y; }
    }
  }
  float vx, vy;
  if (cnt == 0) {
    float2 e = *(const float2*)(ent + (size_t)SENTINEL * 128 + lane * 2);
    vx = e.x; vy = e.y;
  } else {
    float inv = 1.f / (float)cnt;
    vx = sx * inv; vy = sy * inv;
  }
  bf16x2 o; o[0] = (__bf16)vx; o[1] = (__bf16)vy;
  *(bf16x2*)(user_n + (size_t)b * 128 + lane * 2) = o;
}

// ---------------------------------------------------------------------------
// fp8 GEMM body: C = act( (A . W^T) * (1/16) ). W fp8 e4m3 (pre-scaled x16),
// A either fp8 (gll16 staging) or f32 (A_F32: in-register f32->fp8 convert
// during staging; same As layout). Tile (WR*MT*16)x(WC*NT*16), BK=64 (two
// 32-k slabs), 256 threads = 4 waves WR x WC. LDS rows 32 B unpadded.
// MFMA 16x16x32 fp8. Output bf16 (OUT_BF16) or fp8.
// ---------------------------------------------------------------------------
template <int WR, int WC, int MT, int NT, int RELU, bool OUT_BF16, bool A_F32>
__device__ inline void gemm_body_f8(const void* __restrict__ Aptr,
                                    const f8_t* __restrict__ W,
                                    void* __restrict__ Cout,
                                    int M, int N, int K, int bn0, int bm0,
                                    char* lds) {
  constexpr int BM = WR * MT * 16;
  constexpr int BN = WC * NT * 16;
  auto As = (f8_t (*)[BM][32])lds;                        // As[s][r][k]
  auto Bs = (f8_t (*)[BN][32])(lds + (size_t)2 * BM * 32);
  const int tid  = threadIdx.x;
  const int w    = tid >> 6;
  const int lane = tid & 63;
  const int quad = lane >> 4;
  const int l16  = lane & 15;
  const int wr   = w / WC;
  const int wc   = w % WC;
  const int lrow = lane >> 1;        // 0..31 row within 1 KB chunk
  const int lcol = (lane & 1) * 16;  // fp8 col within 32-B slab row

  floatx4 acc[MT][NT];
#pragma unroll
  for (int mt = 0; mt < MT; ++mt)
#pragma unroll
    for (int nt = 0; nt < NT; ++nt) acc[mt][nt] = (floatx4){0.f, 0.f, 0.f, 0.f};

  constexpr int nAc = 2 * (BM / 32);  // 1 KB chunks, slab-major
  constexpr int nBc = 2 * (BN / 32);
  for (int k0 = 0; k0 < K; k0 += 64) {
    __syncthreads();
#pragma unroll
    for (int c = w; c < nAc; c += 4) {
      int s = c / (BM / 32);
      int r = (c % (BM / 32)) * 32;
      if constexpr (A_F32) {
        const float* ap = (const float*)Aptr +
                          (size_t)(bm0 + r + lrow) * K + k0 + s * 32 + lcol;
        float4 a0 = *(const float4*)ap;
        float4 a1 = *(const float4*)(ap + 4);
        float4 a2 = *(const float4*)(ap + 8);
        float4 a3 = *(const float4*)(ap + 12);
        int4 pk;
        pk.x = pack4_fp8(a0, 1.f); pk.y = pack4_fp8(a1, 1.f);
        pk.z = pack4_fp8(a2, 1.f); pk.w = pack4_fp8(a3, 1.f);
        *(int4*)&As[s][r + lrow][lcol] = pk;
      } else {
        gll16((const f8_t*)Aptr + (size_t)(bm0 + r + lrow) * K + k0 + s * 32 + lcol,
              &As[s][r][0]);
      }
    }
#pragma unroll
    for (int c = w; c < nBc; c += 4) {
      int s = c / (BN / 32);
      int r = (c % (BN / 32)) * 32;
      gll16(W + (size_t)(bn0 + r + lrow) * K + k0 + s * 32 + lcol, &Bs[s][r][0]);
    }
    __syncthreads();
#pragma unroll
    for (int s = 0; s < 2; ++s) {
      long af[MT], bfr[NT];
#pragma unroll
      for (int mt = 0; mt < MT; ++mt)
        af[mt] = *(const long*)&As[s][wr * (MT * 16) + mt * 16 + l16][quad * 8];
#pragma unroll
      for (int nt = 0; nt < NT; ++nt)
        bfr[nt] = *(const long*)&Bs[s][wc * (NT * 16) + nt * 16 + l16][quad * 8];
#pragma unroll
      for (int mt = 0; mt < MT; ++mt)
#pragma unroll
        for (int nt = 0; nt < NT; ++nt)
          acc[mt][nt] = __builtin_amdgcn_mfma_f32_16x16x32_fp8_fp8(
              af[mt], bfr[nt], acc[mt][nt], 0, 0, 0);
    }
  }

  const float osc = 0.0625f;  // undo W x16
#pragma unroll
  for (int mt = 0; mt < MT; ++mt) {
    const int row0 = bm0 + wr * (MT * 16) + mt * 16 + quad * 4;
#pragma unroll
    for (int nt = 0; nt < NT; ++nt) {
      const int col = bn0 + wc * (NT * 16) + nt * 16 + l16;
#pragma unroll
      for (int r = 0; r < 4; ++r) {
        float v = acc[mt][nt][r] * osc;
        if (RELU) v = fmaxf(v, 0.f);
        if (OUT_BF16) {
          ((__bf16*)Cout)[(size_t)(row0 + r) * N + col] = (__bf16)v;
        } else {
          int p = __builtin_amdgcn_cvt_pk_fp8_f32(v, v, 0, false);
          ((f8_t*)Cout)[(size_t)(row0 + r) * N + col] = (f8_t)(p & 0xff);
        }
      }
    }
  }
}

template <int WR, int WC, int MT, int NT, int RELU, bool OUT_BF16>
__global__ __launch_bounds__(256) void gemm_f8(const f8_t* __restrict__ A,
                                               const f8_t* __restrict__ W,
                                               void* __restrict__ C,
                                               int M, int N, int K) {
  __shared__ char lds[(size_t)2 * ((WR * MT * 16) + (WC * NT * 16)) * 32];
  gemm_body_f8<WR, WC, MT, NT, RELU, OUT_BF16, false>(
      A, W, C, M, N, K, blockIdx.x * (WC * NT * 16), blockIdx.y * (WR * MT * 16),
      lds);
}

// ---------------------------------------------------------------------------
// gemm1 (A = f32 ctx read directly, fp8 in-register; 64x96 tiles, blocks
// 0..511 = (8 n)x(64 m)) fused with user_n -> user_t transpose (512..639).
// ---------------------------------------------------------------------------
__global__ __launch_bounds__(256) void gemm1_tr(const float* __restrict__ A,
                                                const f8_t* __restrict__ W,
                                                f8_t* __restrict__ C,
                                                const __bf16* __restrict__ un,
                                                __bf16* __restrict__ ut) {
  __shared__ char lds[10240];
  const int bx = blockIdx.x;
  if (bx < 512) {
    gemm_body_f8<2, 2, 2, 3, 1, false, true>(A, W, C, 4096, 768, 1024,
                                             (bx % 8) * 96, (bx / 8) * 64, lds);
    return;
  }
  const int idx = bx - 512;             // 0..127
  const int r0 = (idx & 63) * 64;       // key rows
  const int c0 = (idx >> 6) * 64;       // dim cols
  auto T = (__bf16 (*)[72])lds;
  const int tid = threadIdx.x;
#pragma unroll
  for (int p = 0; p < 2; ++p) {
    int r = (tid >> 3) + p * 32;
    int c = (tid & 7) * 8;
    *(bf16x8*)&T[r][c] = *(const bf16x8*)(un + (size_t)(r0 + r) * 128 + c0 + c);
  }
  __syncthreads();
#pragma unroll
  for (int p = 0; p < 2; ++p) {
    int c = (tid >> 3) + p * 32;
    int r = (tid & 7) * 8;
    bf16x8 v;
#pragma unroll
    for (int j = 0; j < 8; ++j) v[j] = T[r + j][c];
    *(bf16x8*)(ut + (size_t)(c0 + c) * 4096 + r0 + r) = v;
  }
}

// ---------------------------------------------------------------------------
// Flash attention (bf16) + FUSED COMBINE. BM=128 (wave owns 32 q-rows),
// LDS-staged, no max-subtraction (|scores|~1e-2). grid (32 q-tiles, 16
// key-splits) = 512 blocks; 4 chunks of 64 keys per split.
// After writing O_part/lp each block does one agent-scope ACQ_REL arrival on
// done[qtile]; the 16th arriver (only) combines that q-tile's 128 rows:
// out = (sum_s O_s) / (sum_s lp_s) — fixed split order, deterministic.
// No spinning, no grid barrier.
// ---------------------------------------------------------------------------
__global__ __launch_bounds__(256) void flash_attn(const __bf16* __restrict__ Q,
                                                  const __bf16* __restrict__ Un_g,
                                                  const __bf16* __restrict__ Ut_g,
                                                  __bf16* __restrict__ O_part,
                                                  float* __restrict__ lp,
                                                  unsigned* __restrict__ done,
                                                  float* __restrict__ out) {
  __shared__ __bf16 Un[64][136];    // [key][d]   stride 272 B (2-way banks)
  __shared__ __bf16 Ut[128][72];    // [d][key]   stride 144 B
  __shared__ __bf16 Ps[4][32][72];  // per-wave P [qrow 0..31][key], wave-private
  const int tid  = threadIdx.x;
  const int w    = tid >> 6;
  const int lane = tid & 63;
  const int quad = lane >> 4;
  const int l16  = lane & 15;
  const int qtile = blockIdx.x;
  const int qrow0 = qtile * 128;
  const int split = blockIdx.y;
  const float scale = 0.08838834764831845f;  // 1/sqrt(128)

  bf16x8 aq[2][4];
#pragma unroll
  for (int mt = 0; mt < 2; ++mt)
#pragma unroll
    for (int c = 0; c < 4; ++c)
      aq[mt][c] = *(const bf16x8*)(Q + (size_t)(qrow0 + w * 32 + mt * 16 + l16) * 128 +
                                   c * 32 + quad * 8);

  floatx4 o[2][8];
#pragma unroll
  for (int mt = 0; mt < 2; ++mt)
#pragma unroll
    for (int t = 0; t < 8; ++t) o[mt][t] = (floatx4){0.f, 0.f, 0.f, 0.f};
  float lsum[2][4] = {{0.f, 0.f, 0.f, 0.f}, {0.f, 0.f, 0.f, 0.f}};

  for (int chunk = 0; chunk < 4; ++chunk) {
    const int key0 = (split * 4 + chunk) * 64;
    __syncthreads();  // staged buffers safe to overwrite
#pragma unroll
    for (int p = 0; p < 4; ++p) {
      int r = (tid >> 4) + p * 16;
      int c = (tid & 15) * 8;
      *(bf16x8*)&Un[r][c] = *(const bf16x8*)(Un_g + (size_t)(key0 + r) * 128 + c);
    }
#pragma unroll
    for (int p = 0; p < 4; ++p) {
      int d = (tid >> 3) + p * 32;
      int kk = (tid & 7) * 8;
      *(bf16x8*)&Ut[d][kk] = *(const bf16x8*)(Ut_g + (size_t)d * 4096 + key0 + kk);
    }
    __syncthreads();

    // S = Q Uc^T for both m-tiles (bk read once), exp fp32, P -> LDS bf16.
#pragma unroll
    for (int t = 0; t < 4; ++t) {
      bf16x8 bk[4];
#pragma unroll
      for (int c = 0; c < 4; ++c)
        bk[c] = *(const bf16x8*)&Un[t * 16 + l16][c * 32 + quad * 8];
      floatx4 s0 = (floatx4){0.f, 0.f, 0.f, 0.f};
      floatx4 s1 = (floatx4){0.f, 0.f, 0.f, 0.f};
#pragma unroll
      for (int c = 0; c < 4; ++c) {
        s0 = __builtin_amdgcn_mfma_f32_16x16x32_bf16(aq[0][c], bk[c], s0, 0, 0, 0);
        s1 = __builtin_amdgcn_mfma_f32_16x16x32_bf16(aq[1][c], bk[c], s1, 0, 0, 0);
      }
#pragma unroll
      for (int r = 0; r < 4; ++r) {
        float p0 = __expf(s0[r] * scale);
        float p1 = __expf(s1[r] * scale);
        lsum[0][r] += p0;
        lsum[1][r] += p1;
        Ps[w][quad * 4 + r][t * 16 + l16] = (__bf16)p0;
        Ps[w][16 + quad * 4 + r][t * 16 + l16] = (__bf16)p1;
      }
    }
    // Ps wave-private: compiler lgkmcnt ordering suffices, no barrier.

    // O += P @ Uc (bv read once, used by both m-tiles)
#pragma unroll
    for (int c2 = 0; c2 < 2; ++c2) {
      bf16x8 ap0 = *(const bf16x8*)&Ps[w][l16][c2 * 32 + quad * 8];
      bf16x8 ap1 = *(const bf16x8*)&Ps[w][16 + l16][c2 * 32 + quad * 8];
#pragma unroll
      for (int dt = 0; dt < 8; ++dt) {
        bf16x8 bv = *(const bf16x8*)&Ut[dt * 16 + l16][c2 * 32 + quad * 8];
        o[0][dt] = __builtin_amdgcn_mfma_f32_16x16x32_bf16(ap0, bv, o[0][dt], 0, 0, 0);
        o[1][dt] = __builtin_amdgcn_mfma_f32_16x16x32_bf16(ap1, bv, o[1][dt], 0, 0, 0);
      }
    }
  }

  // Row sums: reduce over the 16 key-columns held across l16.
#pragma unroll
  for (int mt = 0; mt < 2; ++mt)
#pragma unroll
    for (int r = 0; r < 4; ++r) {
      float v = lsum[mt][r];
      v += __shfl_xor(v, 1);
      v += __shfl_xor(v, 2);
      v += __shfl_xor(v, 4);
      v += __shfl_xor(v, 8);
      lsum[mt][r] = v;
    }

  __bf16* Ob = O_part + (size_t)split * 524288;
#pragma unroll
  for (int mt = 0; mt < 2; ++mt) {
    const int row0 = qrow0 + w * 32 + mt * 16 + quad * 4;
#pragma unroll
    for (int dt = 0; dt < 8; ++dt) {
#pragma unroll
      for (int r = 0; r < 4; ++r) {
        Ob[(size_t)(row0 + r) * 128 + dt * 16 + l16] = (__bf16)o[mt][dt][r];
      }
    }
    if (l16 == 0) {
#pragma unroll
      for (int r = 0; r < 4; ++r) lp[(size_t)split * 4096 + row0 + r] = lsum[mt][r];
    }
  }

  // ---- fused combine: last arriver for this q-tile does it ----
  __syncthreads();  // all O_part/lp stores issued (vmcnt drained); Un dead
  int* flagp = (int*)&Un[0][0];
  if (tid == 0) {
    __threadfence();  // release this block's stores device-wide
    unsigned old = __hip_atomic_fetch_add(done + qtile, 1u, __ATOMIC_ACQ_REL,
                                          __HIP_MEMORY_SCOPE_AGENT);
    __threadfence();  // acquire: invalidate caches before re-reading O_part
    *flagp = (old == 15u) ? 1 : 0;
  }
  __syncthreads();
  if (*flagp) {
    const int row = qrow0 + (tid >> 1);
    const int col0 = (tid & 1) * 64;
    float den = 0.f;
#pragma unroll
    for (int s = 0; s < 16; ++s) den += lp[(size_t)s * 4096 + row];
    const float inv = 1.f / den;
#pragma unroll
    for (int c8 = 0; c8 < 8; ++c8) {
      float num[8] = {0.f, 0.f, 0.f, 0.f, 0.f, 0.f, 0.f, 0.f};
#pragma unroll
      for (int s = 0; s < 16; ++s) {
        bf16x8 v = *(const bf16x8*)(O_part + (size_t)s * 524288 +
                                    (size_t)row * 128 + col0 + c8 * 8);
#pragma unroll
        for (int j = 0; j < 8; ++j) num[j] += (float)v[j];
      }
      float4 r0 = {num[0] * inv, num[1] * inv, num[2] * inv, num[3] * inv};
      float4 r1 = {num[4] * inv, num[5] * inv, num[6] * inv, num[7] * inv};
      *(float4*)(out + (size_t)row * 128 + col0 + c8 * 8) = r0;
      *(float4*)(out + (size_t)row * 128 + col0 + c8 * 8 + 4) = r1;
    }
  }
}

extern "C" void kernel_launch(void* const* d_in, const int* in_sizes, int n_in,
                              void* d_out, int out_size, void* d_ws, size_t ws_size,
                              hipStream_t stream) {
  (void)in_sizes; (void)n_in; (void)out_size; (void)ws_size;
  const float* ctx      = (const float*)d_in[0];  // [4096,1024]
  const float* ent_embs = (const float*)d_in[1];  // [24636,128]
  const float* W1       = (const float*)d_in[2];  // [768,1024]
  const float* W2       = (const float*)d_in[3];  // [512,768]
  const float* W3       = (const float*)d_in[4];  // [128,512]
  const int*   ent_list = (const int*)d_in[5];    // [4096,50]
  float* out = (float*)d_out;

  // ws layout; peak use ~27 MB + done ctr at 240 MB (ws is 256 MB).
  char* base = (char*)d_ws;
  __bf16* user_n = (__bf16*)(base);                       // 1 MB
  __bf16* user_t = (__bf16*)(base + (1ull << 20));        // 1 MB
  __bf16* qb     = (__bf16*)(base + (2ull << 20));        // 1 MB
  float*  lp     = (float*)(base + (3ull << 20));         // 256 KB [16][4096]
  f8_t*   W1b    = (f8_t*)(base + (4ull << 20));          // 0.75 MB
  f8_t*   W2b    = (f8_t*)(base + 5242880ull);            // 5 MB, 384 KB
  f8_t*   W3b    = (f8_t*)(base + 5636096ull);            // 5.375 MB, 64 KB
  f8_t*   x1b    = (f8_t*)(base + (6ull << 20));          // 3 MB
  f8_t*   x2b    = (f8_t*)(base + (9ull << 20));          // 2 MB
  __bf16* O_part = (__bf16*)(base + (11ull << 20));       // 16 MB (bf16 x 16)
  unsigned* done = (unsigned*)(base + (240ull << 20));    // 32 counters

  hipMemsetAsync(done, 0, 128, stream);

  // 5 dispatches.
  prep_kernel<<<1632, 256, 0, stream>>>(W1, W1b, W2, W2b, W3, W3b,
                                        ent_embs, ent_list, user_n);
  gemm1_tr<<<640, 256, 0, stream>>>(ctx, W1b, x1b, user_n, user_t);
  gemm_f8<2, 2, 2, 2, 1, false><<<dim3(8, 64), 256, 0, stream>>>(
      x1b, W2b, x2b, 4096, 512, 768);
  gemm_f8<2, 2, 1, 2, 0, true><<<dim3(2, 128), 256, 0, stream>>>(
      x2b, W3b, qb, 4096, 128, 512);
  flash_attn<<<dim3(32, 16), 256, 0, stream>>>(qb, user_n, user_t, O_part, lp,
                                               done, out);
}

// Round 12
// 162.343 us; speedup vs baseline: 1.4000x; 1.4000x over previous
//
#include <hip/hip_runtime.h>
#include <hip/hip_bf16.h>

#define SENTINEL 24635

typedef unsigned char f8_t;  // OCP e4m3 storage
using bf16x8  = __attribute__((ext_vector_type(8))) __bf16;
using bf16x2  = __attribute__((ext_vector_type(2))) __bf16;
using floatx4 = __attribute__((ext_vector_type(4))) float;

__device__ inline int pack4_fp8(float4 a, float s) {
  int w = __builtin_amdgcn_cvt_pk_fp8_f32(a.x * s, a.y * s, 0, false);
  return __builtin_amdgcn_cvt_pk_fp8_f32(a.z * s, a.w * s, w, true);
}

// pack 8 scaled floats -> 8 e4m3 bytes
__device__ inline void store_fp8x8(f8_t* d, float4 a, float4 b, float s) {
  int2 v; v.x = pack4_fp8(a, s); v.y = pack4_fp8(b, s);
  *(int2*)d = v;
}

// async global->LDS, 16 B per lane. LDS dest = wave-uniform base + lane*16.
__device__ inline void gll16(const void* g, void* l) {
  __builtin_amdgcn_global_load_lds(
      (const __attribute__((address_space(1))) unsigned int*)g,
      (__attribute__((address_space(3))) unsigned int*)l, 16, 0, 0);
}

// ---------------------------------------------------------------------------
// Prep: f32->fp8 convert of W1/W2/W3 (x16, epilogue undoes; blocks 0..607)
// fused with pool (blocks 608..1631): user_n[b] = bf16 masked mean of
// ent_embs[ent_list[b,:cnt]]; cnt = first-SENTINEL prefix; cnt==0 -> sentinel.
// ---------------------------------------------------------------------------
__global__ __launch_bounds__(256) void prep_kernel(
    const float* __restrict__ s1, f8_t* __restrict__ d1,
    const float* __restrict__ s2, f8_t* __restrict__ d2,
    const float* __restrict__ s3, f8_t* __restrict__ d3,
    const float* __restrict__ ent, const int* __restrict__ ent_list,
    __bf16* __restrict__ user_n) {
  if (blockIdx.x < 608) {
    // sizes in 8-elem units: W1 98304, W2 49152, W3 8192
    int g = blockIdx.x * 256 + threadIdx.x;
    const float* s; f8_t* d; int i;
    if (g < 98304)       { s = s1; d = d1; i = g; }
    else if (g < 147456) { s = s2; d = d2; i = g - 98304; }
    else if (g < 155648) { s = s3; d = d3; i = g - 147456; }
    else return;
    i *= 8;
    float4 a = *(const float4*)(s + i);
    float4 b = *(const float4*)(s + i + 4);
    store_fp8x8(d + i, a, b, 16.f);
    return;
  }
  const int b = (blockIdx.x - 608) * 4 + (threadIdx.x >> 6);
  const int lane = threadIdx.x & 63;
  int myidx = (lane < 50) ? ent_list[b * 50 + lane] : 0;
  unsigned long long m = __ballot(lane < 50 && myidx == SENTINEL);
  const int cnt = (m == 0) ? 50 : (int)__builtin_ctzll(m);

  float sx = 0.f, sy = 0.f;
  for (int l0 = 0; l0 < 50; l0 += 10) {
    if (l0 >= cnt) break;  // wave-uniform
    float2 e[10];
#pragma unroll
    for (int j = 0; j < 10; ++j) {
      int idx = __shfl(myidx, l0 + j);
      e[j] = *(const float2*)(ent + (size_t)idx * 128 + lane * 2);
    }
#pragma unroll
    for (int j = 0; j < 10; ++j) {
      if (l0 + j < cnt) { sx += e[j].x; sy += e[j].y; }
    }
  }
  float vx, vy;
  if (cnt == 0) {
    float2 e = *(const float2*)(ent + (size_t)SENTINEL * 128 + lane * 2);
    vx = e.x; vy = e.y;
  } else {
    float inv = 1.f / (float)cnt;
    vx = sx * inv; vy = sy * inv;
  }
  bf16x2 o; o[0] = (__bf16)vx; o[1] = (__bf16)vy;
  *(bf16x2*)(user_n + (size_t)b * 128 + lane * 2) = o;
}

// ---------------------------------------------------------------------------
// fp8 GEMM body: C = act( (A . W^T) * (1/16) ). W fp8 e4m3 (pre-scaled x16),
// A either fp8 (gll16 staging) or f32 (A_F32: in-register f32->fp8 convert
// during staging; same As layout). Tile (WR*MT*16)x(WC*NT*16), BK=64 (two
// 32-k slabs), 256 threads = 4 waves WR x WC. LDS rows 32 B unpadded.
// MFMA 16x16x32 fp8. Output bf16 (OUT_BF16) or fp8.
// ---------------------------------------------------------------------------
template <int WR, int WC, int MT, int NT, int RELU, bool OUT_BF16, bool A_F32>
__device__ inline void gemm_body_f8(const void* __restrict__ Aptr,
                                    const f8_t* __restrict__ W,
                                    void* __restrict__ Cout,
                                    int M, int N, int K, int bn0, int bm0,
                                    char* lds) {
  constexpr int BM = WR * MT * 16;
  constexpr int BN = WC * NT * 16;
  auto As = (f8_t (*)[BM][32])lds;                        // As[s][r][k]
  auto Bs = (f8_t (*)[BN][32])(lds + (size_t)2 * BM * 32);
  const int tid  = threadIdx.x;
  const int w    = tid >> 6;
  const int lane = tid & 63;
  const int quad = lane >> 4;
  const int l16  = lane & 15;
  const int wr   = w / WC;
  const int wc   = w % WC;
  const int lrow = lane >> 1;        // 0..31 row within 1 KB chunk
  const int lcol = (lane & 1) * 16;  // fp8 col within 32-B slab row

  floatx4 acc[MT][NT];
#pragma unroll
  for (int mt = 0; mt < MT; ++mt)
#pragma unroll
    for (int nt = 0; nt < NT; ++nt) acc[mt][nt] = (floatx4){0.f, 0.f, 0.f, 0.f};

  constexpr int nAc = 2 * (BM / 32);  // 1 KB chunks, slab-major
  constexpr int nBc = 2 * (BN / 32);
  for (int k0 = 0; k0 < K; k0 += 64) {
    __syncthreads();
#pragma unroll
    for (int c = w; c < nAc; c += 4) {
      int s = c / (BM / 32);
      int r = (c % (BM / 32)) * 32;
      if constexpr (A_F32) {
        const float* ap = (const float*)Aptr +
                          (size_t)(bm0 + r + lrow) * K + k0 + s * 32 + lcol;
        float4 a0 = *(const float4*)ap;
        float4 a1 = *(const float4*)(ap + 4);
        float4 a2 = *(const float4*)(ap + 8);
        float4 a3 = *(const float4*)(ap + 12);
        int4 pk;
        pk.x = pack4_fp8(a0, 1.f); pk.y = pack4_fp8(a1, 1.f);
        pk.z = pack4_fp8(a2, 1.f); pk.w = pack4_fp8(a3, 1.f);
        *(int4*)&As[s][r + lrow][lcol] = pk;
      } else {
        gll16((const f8_t*)Aptr + (size_t)(bm0 + r + lrow) * K + k0 + s * 32 + lcol,
              &As[s][r][0]);
      }
    }
#pragma unroll
    for (int c = w; c < nBc; c += 4) {
      int s = c / (BN / 32);
      int r = (c % (BN / 32)) * 32;
      gll16(W + (size_t)(bn0 + r + lrow) * K + k0 + s * 32 + lcol, &Bs[s][r][0]);
    }
    __syncthreads();
#pragma unroll
    for (int s = 0; s < 2; ++s) {
      long af[MT], bfr[NT];
#pragma unroll
      for (int mt = 0; mt < MT; ++mt)
        af[mt] = *(const long*)&As[s][wr * (MT * 16) + mt * 16 + l16][quad * 8];
#pragma unroll
      for (int nt = 0; nt < NT; ++nt)
        bfr[nt] = *(const long*)&Bs[s][wc * (NT * 16) + nt * 16 + l16][quad * 8];
#pragma unroll
      for (int mt = 0; mt < MT; ++mt)
#pragma unroll
        for (int nt = 0; nt < NT; ++nt)
          acc[mt][nt] = __builtin_amdgcn_mfma_f32_16x16x32_fp8_fp8(
              af[mt], bfr[nt], acc[mt][nt], 0, 0, 0);
    }
  }

  const float osc = 0.0625f;  // undo W x16
#pragma unroll
  for (int mt = 0; mt < MT; ++mt) {
    const int row0 = bm0 + wr * (MT * 16) + mt * 16 + quad * 4;
#pragma unroll
    for (int nt = 0; nt < NT; ++nt) {
      const int col = bn0 + wc * (NT * 16) + nt * 16 + l16;
#pragma unroll
      for (int r = 0; r < 4; ++r) {
        float v = acc[mt][nt][r] * osc;
        if (RELU) v = fmaxf(v, 0.f);
        if (OUT_BF16) {
          ((__bf16*)Cout)[(size_t)(row0 + r) * N + col] = (__bf16)v;
        } else {
          int p = __builtin_amdgcn_cvt_pk_fp8_f32(v, v, 0, false);
          ((f8_t*)Cout)[(size_t)(row0 + r) * N + col] = (f8_t)(p & 0xff);
        }
      }
    }
  }
}

template <int WR, int WC, int MT, int NT, int RELU, bool OUT_BF16>
__global__ __launch_bounds__(256) void gemm_f8(const f8_t* __restrict__ A,
                                               const f8_t* __restrict__ W,
                                               void* __restrict__ C,
                                               int M, int N, int K) {
  __shared__ char lds[(size_t)2 * ((WR * MT * 16) + (WC * NT * 16)) * 32];
  gemm_body_f8<WR, WC, MT, NT, RELU, OUT_BF16, false>(
      A, W, C, M, N, K, blockIdx.x * (WC * NT * 16), blockIdx.y * (WR * MT * 16),
      lds);
}

// ---------------------------------------------------------------------------
// gemm1 (A = f32 ctx read directly, fp8 in-register; 64x96 tiles, blocks
// 0..511 = (8 n)x(64 m)) fused with user_n -> user_t transpose (512..639).
// ---------------------------------------------------------------------------
__global__ __launch_bounds__(256) void gemm1_tr(const float* __restrict__ A,
                                                const f8_t* __restrict__ W,
                                                f8_t* __restrict__ C,
                                                const __bf16* __restrict__ un,
                                                __bf16* __restrict__ ut) {
  __shared__ char lds[10240];
  const int bx = blockIdx.x;
  if (bx < 512) {
    gemm_body_f8<2, 2, 2, 3, 1, false, true>(A, W, C, 4096, 768, 1024,
                                             (bx % 8) * 96, (bx / 8) * 64, lds);
    return;
  }
  const int idx = bx - 512;             // 0..127
  const int r0 = (idx & 63) * 64;       // key rows
  const int c0 = (idx >> 6) * 64;       // dim cols
  auto T = (__bf16 (*)[72])lds;
  const int tid = threadIdx.x;
#pragma unroll
  for (int p = 0; p < 2; ++p) {
    int r = (tid >> 3) + p * 32;
    int c = (tid & 7) * 8;
    *(bf16x8*)&T[r][c] = *(const bf16x8*)(un + (size_t)(r0 + r) * 128 + c0 + c);
  }
  __syncthreads();
#pragma unroll
  for (int p = 0; p < 2; ++p) {
    int c = (tid >> 3) + p * 32;
    int r = (tid & 7) * 8;
    bf16x8 v;
#pragma unroll
    for (int j = 0; j < 8; ++j) v[j] = T[r + j][c];
    *(bf16x8*)(ut + (size_t)(c0 + c) * 4096 + r0 + r) = v;
  }
}

// ---------------------------------------------------------------------------
// Flash attention (bf16), BM=128 (wave owns 32 q-rows = 2 m-tiles), LDS-staged,
// no max-subtraction (|scores| ~ 1e-2). grid (32 q-tiles, 16 key-splits) =
// 512 blocks; 4 chunks of 64 keys per split; LDS 54272 -> 2 blocks/CU.
//   O_part[split] = sum_chunks exp(Q Uc^T * scale) @ Uc ; lp[split][q] = row sums
// NO fences / atomics (R11 showed device-scope fences cost ~60 us here).
// ---------------------------------------------------------------------------
__global__ __launch_bounds__(256) void flash_attn(const __bf16* __restrict__ Q,
                                                  const __bf16* __restrict__ Un_g,
                                                  const __bf16* __restrict__ Ut_g,
                                                  __bf16* __restrict__ O_part,
                                                  float* __restrict__ lp) {
  __shared__ __bf16 Un[64][136];    // [key][d]   stride 272 B (2-way banks)
  __shared__ __bf16 Ut[128][72];    // [d][key]   stride 144 B
  __shared__ __bf16 Ps[4][32][72];  // per-wave P [qrow 0..31][key], wave-private
  const int tid  = threadIdx.x;
  const int w    = tid >> 6;
  const int lane = tid & 63;
  const int quad = lane >> 4;
  const int l16  = lane & 15;
  const int qrow0 = blockIdx.x * 128;
  const int split = blockIdx.y;
  const float scale = 0.08838834764831845f;  // 1/sqrt(128)

  bf16x8 aq[2][4];
#pragma unroll
  for (int mt = 0; mt < 2; ++mt)
#pragma unroll
    for (int c = 0; c < 4; ++c)
      aq[mt][c] = *(const bf16x8*)(Q + (size_t)(qrow0 + w * 32 + mt * 16 + l16) * 128 +
                                   c * 32 + quad * 8);

  floatx4 o[2][8];
#pragma unroll
  for (int mt = 0; mt < 2; ++mt)
#pragma unroll
    for (int t = 0; t < 8; ++t) o[mt][t] = (floatx4){0.f, 0.f, 0.f, 0.f};
  float lsum[2][4] = {{0.f, 0.f, 0.f, 0.f}, {0.f, 0.f, 0.f, 0.f}};

  for (int chunk = 0; chunk < 4; ++chunk) {
    const int key0 = (split * 4 + chunk) * 64;
    __syncthreads();  // staged buffers safe to overwrite
#pragma unroll
    for (int p = 0; p < 4; ++p) {
      int r = (tid >> 4) + p * 16;
      int c = (tid & 15) * 8;
      *(bf16x8*)&Un[r][c] = *(const bf16x8*)(Un_g + (size_t)(key0 + r) * 128 + c);
    }
#pragma unroll
    for (int p = 0; p < 4; ++p) {
      int d = (tid >> 3) + p * 32;
      int kk = (tid & 7) * 8;
      *(bf16x8*)&Ut[d][kk] = *(const bf16x8*)(Ut_g + (size_t)d * 4096 + key0 + kk);
    }
    __syncthreads();

    // S = Q Uc^T for both m-tiles (bk read once), exp fp32, P -> LDS bf16.
#pragma unroll
    for (int t = 0; t < 4; ++t) {
      bf16x8 bk[4];
#pragma unroll
      for (int c = 0; c < 4; ++c)
        bk[c] = *(const bf16x8*)&Un[t * 16 + l16][c * 32 + quad * 8];
      floatx4 s0 = (floatx4){0.f, 0.f, 0.f, 0.f};
      floatx4 s1 = (floatx4){0.f, 0.f, 0.f, 0.f};
#pragma unroll
      for (int c = 0; c < 4; ++c) {
        s0 = __builtin_amdgcn_mfma_f32_16x16x32_bf16(aq[0][c], bk[c], s0, 0, 0, 0);
        s1 = __builtin_amdgcn_mfma_f32_16x16x32_bf16(aq[1][c], bk[c], s1, 0, 0, 0);
      }
#pragma unroll
      for (int r = 0; r < 4; ++r) {
        float p0 = __expf(s0[r] * scale);
        float p1 = __expf(s1[r] * scale);
        lsum[0][r] += p0;
        lsum[1][r] += p1;
        Ps[w][quad * 4 + r][t * 16 + l16] = (__bf16)p0;
        Ps[w][16 + quad * 4 + r][t * 16 + l16] = (__bf16)p1;
      }
    }
    // Ps wave-private: compiler lgkmcnt ordering suffices, no barrier.

    // O += P @ Uc (bv read once, used by both m-tiles)
#pragma unroll
    for (int c2 = 0; c2 < 2; ++c2) {
      bf16x8 ap0 = *(const bf16x8*)&Ps[w][l16][c2 * 32 + quad * 8];
      bf16x8 ap1 = *(const bf16x8*)&Ps[w][16 + l16][c2 * 32 + quad * 8];
#pragma unroll
      for (int dt = 0; dt < 8; ++dt) {
        bf16x8 bv = *(const bf16x8*)&Ut[dt * 16 + l16][c2 * 32 + quad * 8];
        o[0][dt] = __builtin_amdgcn_mfma_f32_16x16x32_bf16(ap0, bv, o[0][dt], 0, 0, 0);
        o[1][dt] = __builtin_amdgcn_mfma_f32_16x16x32_bf16(ap1, bv, o[1][dt], 0, 0, 0);
      }
    }
  }

  // Row sums: reduce over the 16 key-columns held across l16.
#pragma unroll
  for (int mt = 0; mt < 2; ++mt)
#pragma unroll
    for (int r = 0; r < 4; ++r) {
      float v = lsum[mt][r];
      v += __shfl_xor(v, 1);
      v += __shfl_xor(v, 2);
      v += __shfl_xor(v, 4);
      v += __shfl_xor(v, 8);
      lsum[mt][r] = v;
    }

  __bf16* Ob = O_part + (size_t)split * 524288;
#pragma unroll
  for (int mt = 0; mt < 2; ++mt) {
    const int row0 = qrow0 + w * 32 + mt * 16 + quad * 4;
#pragma unroll
    for (int dt = 0; dt < 8; ++dt) {
#pragma unroll
      for (int r = 0; r < 4; ++r) {
        Ob[(size_t)(row0 + r) * 128 + dt * 16 + l16] = (__bf16)o[mt][dt][r];
      }
    }
    if (l16 == 0) {
#pragma unroll
      for (int r = 0; r < 4; ++r) lp[(size_t)split * 4096 + row0 + r] = lsum[mt][r];
    }
  }
}

// ---------------------------------------------------------------------------
// Combine 16 key-splits: out = (sum_s O_s) / (sum_s lp[s][row]). 8 elems/thr.
// ---------------------------------------------------------------------------
__global__ __launch_bounds__(256) void combine_kernel(const __bf16* __restrict__ Op,
                                                      const float* __restrict__ lp,
                                                      float* __restrict__ out) {
  const int i = (blockIdx.x * 256 + threadIdx.x) * 8;  // 0 .. 524287 step 8
  const int row = i >> 7;
  float num[8] = {0.f, 0.f, 0.f, 0.f, 0.f, 0.f, 0.f, 0.f};
  float den = 0.f;
#pragma unroll
  for (int s = 0; s < 16; ++s) {
    bf16x8 v = *(const bf16x8*)(Op + (size_t)s * 524288 + i);
#pragma unroll
    for (int j = 0; j < 8; ++j) num[j] += (float)v[j];
    den += lp[(size_t)s * 4096 + row];
  }
  float inv = 1.f / den;
  float4 r0 = {num[0] * inv, num[1] * inv, num[2] * inv, num[3] * inv};
  float4 r1 = {num[4] * inv, num[5] * inv, num[6] * inv, num[7] * inv};
  *(float4*)(out + i) = r0;
  *(float4*)(out + i + 4) = r1;
}

extern "C" void kernel_launch(void* const* d_in, const int* in_sizes, int n_in,
                              void* d_out, int out_size, void* d_ws, size_t ws_size,
                              hipStream_t stream) {
  (void)in_sizes; (void)n_in; (void)out_size; (void)ws_size;
  const float* ctx      = (const float*)d_in[0];  // [4096,1024]
  const float* ent_embs = (const float*)d_in[1];  // [24636,128]
  const float* W1       = (const float*)d_in[2];  // [768,1024]
  const float* W2       = (const float*)d_in[3];  // [512,768]
  const float* W3       = (const float*)d_in[4];  // [128,512]
  const int*   ent_list = (const int*)d_in[5];    // [4096,50]
  float* out = (float*)d_out;

  // ws layout; peak use ~27 MB (ws is 256 MB).
  char* base = (char*)d_ws;
  __bf16* user_n = (__bf16*)(base);                       // 1 MB
  __bf16* user_t = (__bf16*)(base + (1ull << 20));        // 1 MB
  __bf16* qb     = (__bf16*)(base + (2ull << 20));        // 1 MB
  float*  lp     = (float*)(base + (3ull << 20));         // 256 KB [16][4096]
  f8_t*   W1b    = (f8_t*)(base + (4ull << 20));          // 0.75 MB
  f8_t*   W2b    = (f8_t*)(base + 5242880ull);            // 5 MB, 384 KB
  f8_t*   W3b    = (f8_t*)(base + 5636096ull);            // 5.375 MB, 64 KB
  f8_t*   x1b    = (f8_t*)(base + (6ull << 20));          // 3 MB
  f8_t*   x2b    = (f8_t*)(base + (9ull << 20));          // 2 MB
  __bf16* O_part = (__bf16*)(base + (11ull << 20));       // 16 MB (bf16 x 16)

  // 6 dispatches.
  prep_kernel<<<1632, 256, 0, stream>>>(W1, W1b, W2, W2b, W3, W3b,
                                        ent_embs, ent_list, user_n);
  gemm1_tr<<<640, 256, 0, stream>>>(ctx, W1b, x1b, user_n, user_t);
  gemm_f8<2, 2, 2, 2, 1, false><<<dim3(8, 64), 256, 0, stream>>>(
      x1b, W2b, x2b, 4096, 512, 768);
  gemm_f8<2, 2, 1, 2, 0, true><<<dim3(2, 128), 256, 0, stream>>>(
      x2b, W3b, qb, 4096, 128, 512);
  flash_attn<<<dim3(32, 16), 256, 0, stream>>>(qb, user_n, user_t, O_part, lp);
  combine_kernel<<<256, 256, 0, stream>>>(O_part, lp, out);
}

// Round 13
// 155.328 us; speedup vs baseline: 1.4632x; 1.0452x over previous
//
#include <hip/hip_runtime.h>
#include <hip/hip_bf16.h>

#define SENTINEL 24635

typedef unsigned char f8_t;  // OCP e4m3 storage
using bf16x8  = __attribute__((ext_vector_type(8))) __bf16;
using bf16x2  = __attribute__((ext_vector_type(2))) __bf16;
using floatx4 = __attribute__((ext_vector_type(4))) float;

__device__ inline int pack4_fp8(float4 a, float s) {
  int w = __builtin_amdgcn_cvt_pk_fp8_f32(a.x * s, a.y * s, 0, false);
  return __builtin_amdgcn_cvt_pk_fp8_f32(a.z * s, a.w * s, w, true);
}

// pack 8 scaled floats -> 8 e4m3 bytes
__device__ inline void store_fp8x8(f8_t* d, float4 a, float4 b, float s) {
  int2 v; v.x = pack4_fp8(a, s); v.y = pack4_fp8(b, s);
  *(int2*)d = v;
}

// async global->LDS, 16 B per lane. LDS dest = wave-uniform base + lane*16.
__device__ inline void gll16(const void* g, void* l) {
  __builtin_amdgcn_global_load_lds(
      (const __attribute__((address_space(1))) unsigned int*)g,
      (__attribute__((address_space(3))) unsigned int*)l, 16, 0, 0);
}

// ---------------------------------------------------------------------------
// Prep: f32->fp8 convert of ctx (x1) and W1/W2/W3 (x16, epilogue undoes)
// (blocks 0..2655, 8 elems/thread) fused with pool (blocks 2656..3679):
// user_n[b] = bf16 masked mean of ent_embs[ent_list[b,:cnt]].
// NOTE (R12 lesson): ctx must be pre-converted — gemm1 refetches A 8x, and
// fp8 refetch is 4x cheaper than f32 refetch.
// ---------------------------------------------------------------------------
__global__ __launch_bounds__(256) void prep_kernel(
    const float* __restrict__ s0, f8_t* __restrict__ d0,
    const float* __restrict__ s1, f8_t* __restrict__ d1,
    const float* __restrict__ s2, f8_t* __restrict__ d2,
    const float* __restrict__ s3, f8_t* __restrict__ d3,
    const float* __restrict__ ent, const int* __restrict__ ent_list,
    __bf16* __restrict__ user_n) {
  if (blockIdx.x < 2656) {
    // sizes in 8-elem units: ctx 524288, W1 98304, W2 49152, W3 8192
    int g = blockIdx.x * 256 + threadIdx.x;
    const float* s; f8_t* d; int i; float sc;
    if (g < 524288)      { s = s0; d = d0; i = g;          sc = 1.f;  }
    else if (g < 622592) { s = s1; d = d1; i = g - 524288; sc = 16.f; }
    else if (g < 671744) { s = s2; d = d2; i = g - 622592; sc = 16.f; }
    else if (g < 679936) { s = s3; d = d3; i = g - 671744; sc = 16.f; }
    else return;
    i *= 8;
    float4 a = *(const float4*)(s + i);
    float4 b = *(const float4*)(s + i + 4);
    store_fp8x8(d + i, a, b, sc);
    return;
  }
  const int b = (blockIdx.x - 2656) * 4 + (threadIdx.x >> 6);
  const int lane = threadIdx.x & 63;
  int myidx = (lane < 50) ? ent_list[b * 50 + lane] : 0;
  unsigned long long m = __ballot(lane < 50 && myidx == SENTINEL);
  const int cnt = (m == 0) ? 50 : (int)__builtin_ctzll(m);

  float sx = 0.f, sy = 0.f;
  for (int l0 = 0; l0 < 50; l0 += 10) {
    if (l0 >= cnt) break;  // wave-uniform
    float2 e[10];
#pragma unroll
    for (int j = 0; j < 10; ++j) {
      int idx = __shfl(myidx, l0 + j);
      e[j] = *(const float2*)(ent + (size_t)idx * 128 + lane * 2);
    }
#pragma unroll
    for (int j = 0; j < 10; ++j) {
      if (l0 + j < cnt) { sx += e[j].x; sy += e[j].y; }
    }
  }
  float vx, vy;
  if (cnt == 0) {
    float2 e = *(const float2*)(ent + (size_t)SENTINEL * 128 + lane * 2);
    vx = e.x; vy = e.y;
  } else {
    float inv = 1.f / (float)cnt;
    vx = sx * inv; vy = sy * inv;
  }
  bf16x2 o; o[0] = (__bf16)vx; o[1] = (__bf16)vy;
  *(bf16x2*)(user_n + (size_t)b * 128 + lane * 2) = o;
}

// ---------------------------------------------------------------------------
// fp8 GEMM body: C = act( (A . W^T) * (1/16) ), A,W fp8 e4m3 row-major
// (K contiguous). Tile (WR*MT*16) x (WC*NT*16), BK=64 (two 32-k slabs),
// 256 threads = 4 waves WR x WC. LDS rows 32 B unpadded (m97-style);
// gll16 chunks = 32 rows x 32 B. MFMA 16x16x32 fp8.
// Output: bf16 (OUT_BF16) or fp8 (unscaled activations).
// ---------------------------------------------------------------------------
template <int WR, int WC, int MT, int NT, int RELU, bool OUT_BF16>
__device__ inline void gemm_body_f8(const f8_t* __restrict__ A,
                                    const f8_t* __restrict__ W,
                                    void* __restrict__ Cout,
                                    int M, int N, int K, int bn0, int bm0,
                                    char* lds) {
  constexpr int BM = WR * MT * 16;
  constexpr int BN = WC * NT * 16;
  auto As = (f8_t (*)[BM][32])lds;                        // As[s][r][k]
  auto Bs = (f8_t (*)[BN][32])(lds + (size_t)2 * BM * 32);
  const int tid  = threadIdx.x;
  const int w    = tid >> 6;
  const int lane = tid & 63;
  const int quad = lane >> 4;
  const int l16  = lane & 15;
  const int wr   = w / WC;
  const int wc   = w % WC;
  const int lrow = lane >> 1;        // 0..31 row within 1 KB chunk
  const int lcol = (lane & 1) * 16;  // fp8 col within 32-B slab row

  floatx4 acc[MT][NT];
#pragma unroll
  for (int mt = 0; mt < MT; ++mt)
#pragma unroll
    for (int nt = 0; nt < NT; ++nt) acc[mt][nt] = (floatx4){0.f, 0.f, 0.f, 0.f};

  constexpr int nAc = 2 * (BM / 32);  // 1 KB chunks, slab-major
  constexpr int nBc = 2 * (BN / 32);
  for (int k0 = 0; k0 < K; k0 += 64) {
    __syncthreads();
#pragma unroll
    for (int c = w; c < nAc; c += 4) {
      int s = c / (BM / 32);
      int r = (c % (BM / 32)) * 32;
      gll16(A + (size_t)(bm0 + r + lrow) * K + k0 + s * 32 + lcol, &As[s][r][0]);
    }
#pragma unroll
    for (int c = w; c < nBc; c += 4) {
      int s = c / (BN / 32);
      int r = (c % (BN / 32)) * 32;
      gll16(W + (size_t)(bn0 + r + lrow) * K + k0 + s * 32 + lcol, &Bs[s][r][0]);
    }
    __syncthreads();
#pragma unroll
    for (int s = 0; s < 2; ++s) {
      long af[MT], bfr[NT];
#pragma unroll
      for (int mt = 0; mt < MT; ++mt)
        af[mt] = *(const long*)&As[s][wr * (MT * 16) + mt * 16 + l16][quad * 8];
#pragma unroll
      for (int nt = 0; nt < NT; ++nt)
        bfr[nt] = *(const long*)&Bs[s][wc * (NT * 16) + nt * 16 + l16][quad * 8];
#pragma unroll
      for (int mt = 0; mt < MT; ++mt)
#pragma unroll
        for (int nt = 0; nt < NT; ++nt)
          acc[mt][nt] = __builtin_amdgcn_mfma_f32_16x16x32_fp8_fp8(
              af[mt], bfr[nt], acc[mt][nt], 0, 0, 0);
    }
  }

  const float osc = 0.0625f;  // undo W x16
#pragma unroll
  for (int mt = 0; mt < MT; ++mt) {
    const int row0 = bm0 + wr * (MT * 16) + mt * 16 + quad * 4;
#pragma unroll
    for (int nt = 0; nt < NT; ++nt) {
      const int col = bn0 + wc * (NT * 16) + nt * 16 + l16;
#pragma unroll
      for (int r = 0; r < 4; ++r) {
        float v = acc[mt][nt][r] * osc;
        if (RELU) v = fmaxf(v, 0.f);
        if (OUT_BF16) {
          ((__bf16*)Cout)[(size_t)(row0 + r) * N + col] = (__bf16)v;
        } else {
          int p = __builtin_amdgcn_cvt_pk_fp8_f32(v, v, 0, false);
          ((f8_t*)Cout)[(size_t)(row0 + r) * N + col] = (f8_t)(p & 0xff);
        }
      }
    }
  }
}

template <int WR, int WC, int MT, int NT, int RELU, bool OUT_BF16>
__global__ __launch_bounds__(256) void gemm_f8(const f8_t* __restrict__ A,
                                               const f8_t* __restrict__ W,
                                               void* __restrict__ C,
                                               int M, int N, int K) {
  __shared__ char lds[(size_t)2 * ((WR * MT * 16) + (WC * NT * 16)) * 32];
  gemm_body_f8<WR, WC, MT, NT, RELU, OUT_BF16>(
      A, W, C, M, N, K, blockIdx.x * (WC * NT * 16), blockIdx.y * (WR * MT * 16),
      lds);
}

// ---------------------------------------------------------------------------
// gemm1 (fp8, 64x96 tiles, blocks 0..511 = (8 n)x(64 m)) fused with the
// user_n -> user_t bf16 transpose (blocks 512..639, 64x64 tiles via LDS).
// ---------------------------------------------------------------------------
__global__ __launch_bounds__(256) void gemm1_tr(const f8_t* __restrict__ A,
                                                const f8_t* __restrict__ W,
                                                f8_t* __restrict__ C,
                                                const __bf16* __restrict__ un,
                                                __bf16* __restrict__ ut) {
  __shared__ char lds[10240];
  const int bx = blockIdx.x;
  if (bx < 512) {
    gemm_body_f8<2, 2, 2, 3, 1, false>(A, W, C, 4096, 768, 1024,
                                       (bx % 8) * 96, (bx / 8) * 64, lds);
    return;
  }
  const int idx = bx - 512;             // 0..127
  const int r0 = (idx & 63) * 64;       // key rows
  const int c0 = (idx >> 6) * 64;       // dim cols
  auto T = (__bf16 (*)[72])lds;
  const int tid = threadIdx.x;
#pragma unroll
  for (int p = 0; p < 2; ++p) {
    int r = (tid >> 3) + p * 32;
    int c = (tid & 7) * 8;
    *(bf16x8*)&T[r][c] = *(const bf16x8*)(un + (size_t)(r0 + r) * 128 + c0 + c);
  }
  __syncthreads();
#pragma unroll
  for (int p = 0; p < 2; ++p) {
    int c = (tid >> 3) + p * 32;
    int r = (tid & 7) * 8;
    bf16x8 v;
#pragma unroll
    for (int j = 0; j < 8; ++j) v[j] = T[r + j][c];
    *(bf16x8*)(ut + (size_t)(c0 + c) * 4096 + r0 + r) = v;
  }
}

// ---------------------------------------------------------------------------
// Flash attention (bf16), BM=128 (wave owns 32 q-rows = 2 m-tiles), LDS-staged,
// no max-subtraction (|scores| ~ 1e-2). grid (32 q-tiles, 16 key-splits) =
// 512 blocks; 4 chunks of 64 keys per split; LDS 54272 -> 2 blocks/CU.
//   O_part[split] = sum_chunks exp(Q Uc^T * scale) @ Uc ; lp[split][q] = row sums
// NO fences/atomics (R11: device-scope fences cost ~60 us here).
// ---------------------------------------------------------------------------
__global__ __launch_bounds__(256) void flash_attn(const __bf16* __restrict__ Q,
                                                  const __bf16* __restrict__ Un_g,
                                                  const __bf16* __restrict__ Ut_g,
                                                  __bf16* __restrict__ O_part,
                                                  float* __restrict__ lp) {
  __shared__ __bf16 Un[64][136];    // [key][d]   stride 272 B (2-way banks)
  __shared__ __bf16 Ut[128][72];    // [d][key]   stride 144 B
  __shared__ __bf16 Ps[4][32][72];  // per-wave P [qrow 0..31][key], wave-private
  const int tid  = threadIdx.x;
  const int w    = tid >> 6;
  const int lane = tid & 63;
  const int quad = lane >> 4;
  const int l16  = lane & 15;
  const int qrow0 = blockIdx.x * 128;
  const int split = blockIdx.y;
  const float scale = 0.08838834764831845f;  // 1/sqrt(128)

  bf16x8 aq[2][4];
#pragma unroll
  for (int mt = 0; mt < 2; ++mt)
#pragma unroll
    for (int c = 0; c < 4; ++c)
      aq[mt][c] = *(const bf16x8*)(Q + (size_t)(qrow0 + w * 32 + mt * 16 + l16) * 128 +
                                   c * 32 + quad * 8);

  floatx4 o[2][8];
#pragma unroll
  for (int mt = 0; mt < 2; ++mt)
#pragma unroll
    for (int t = 0; t < 8; ++t) o[mt][t] = (floatx4){0.f, 0.f, 0.f, 0.f};
  float lsum[2][4] = {{0.f, 0.f, 0.f, 0.f}, {0.f, 0.f, 0.f, 0.f}};

  for (int chunk = 0; chunk < 4; ++chunk) {
    const int key0 = (split * 4 + chunk) * 64;
    __syncthreads();  // staged buffers safe to overwrite
#pragma unroll
    for (int p = 0; p < 4; ++p) {
      int r = (tid >> 4) + p * 16;
      int c = (tid & 15) * 8;
      *(bf16x8*)&Un[r][c] = *(const bf16x8*)(Un_g + (size_t)(key0 + r) * 128 + c);
    }
#pragma unroll
    for (int p = 0; p < 4; ++p) {
      int d = (tid >> 3) + p * 32;
      int kk = (tid & 7) * 8;
      *(bf16x8*)&Ut[d][kk] = *(const bf16x8*)(Ut_g + (size_t)d * 4096 + key0 + kk);
    }
    __syncthreads();

    // S = Q Uc^T for both m-tiles (bk read once), exp fp32, P -> LDS bf16.
#pragma unroll
    for (int t = 0; t < 4; ++t) {
      bf16x8 bk[4];
#pragma unroll
      for (int c = 0; c < 4; ++c)
        bk[c] = *(const bf16x8*)&Un[t * 16 + l16][c * 32 + quad * 8];
      floatx4 s0 = (floatx4){0.f, 0.f, 0.f, 0.f};
      floatx4 s1 = (floatx4){0.f, 0.f, 0.f, 0.f};
#pragma unroll
      for (int c = 0; c < 4; ++c) {
        s0 = __builtin_amdgcn_mfma_f32_16x16x32_bf16(aq[0][c], bk[c], s0, 0, 0, 0);
        s1 = __builtin_amdgcn_mfma_f32_16x16x32_bf16(aq[1][c], bk[c], s1, 0, 0, 0);
      }
#pragma unroll
      for (int r = 0; r < 4; ++r) {
        float p0 = __expf(s0[r] * scale);
        float p1 = __expf(s1[r] * scale);
        lsum[0][r] += p0;
        lsum[1][r] += p1;
        Ps[w][quad * 4 + r][t * 16 + l16] = (__bf16)p0;
        Ps[w][16 + quad * 4 + r][t * 16 + l16] = (__bf16)p1;
      }
    }
    // Ps wave-private: compiler lgkmcnt ordering suffices, no barrier.

    // O += P @ Uc (bv read once, used by both m-tiles)
#pragma unroll
    for (int c2 = 0; c2 < 2; ++c2) {
      bf16x8 ap0 = *(const bf16x8*)&Ps[w][l16][c2 * 32 + quad * 8];
      bf16x8 ap1 = *(const bf16x8*)&Ps[w][16 + l16][c2 * 32 + quad * 8];
#pragma unroll
      for (int dt = 0; dt < 8; ++dt) {
        bf16x8 bv = *(const bf16x8*)&Ut[dt * 16 + l16][c2 * 32 + quad * 8];
        o[0][dt] = __builtin_amdgcn_mfma_f32_16x16x32_bf16(ap0, bv, o[0][dt], 0, 0, 0);
        o[1][dt] = __builtin_amdgcn_mfma_f32_16x16x32_bf16(ap1, bv, o[1][dt], 0, 0, 0);
      }
    }
  }

  // Row sums: reduce over the 16 key-columns held across l16.
#pragma unroll
  for (int mt = 0; mt < 2; ++mt)
#pragma unroll
    for (int r = 0; r < 4; ++r) {
      float v = lsum[mt][r];
      v += __shfl_xor(v, 1);
      v += __shfl_xor(v, 2);
      v += __shfl_xor(v, 4);
      v += __shfl_xor(v, 8);
      lsum[mt][r] = v;
    }

  __bf16* Ob = O_part + (size_t)split * 524288;
#pragma unroll
  for (int mt = 0; mt < 2; ++mt) {
    const int row0 = qrow0 + w * 32 + mt * 16 + quad * 4;
#pragma unroll
    for (int dt = 0; dt < 8; ++dt) {
#pragma unroll
      for (int r = 0; r < 4; ++r) {
        Ob[(size_t)(row0 + r) * 128 + dt * 16 + l16] = (__bf16)o[mt][dt][r];
      }
    }
    if (l16 == 0) {
#pragma unroll
      for (int r = 0; r < 4; ++r) lp[(size_t)split * 4096 + row0 + r] = lsum[mt][r];
    }
  }
}

// ---------------------------------------------------------------------------
// Combine 16 key-splits: out = (sum_s O_s) / (sum_s lp[s][row]). 8 elems/thr.
// ---------------------------------------------------------------------------
__global__ __launch_bounds__(256) void combine_kernel(const __bf16* __restrict__ Op,
                                                      const float* __restrict__ lp,
                                                      float* __restrict__ out) {
  const int i = (blockIdx.x * 256 + threadIdx.x) * 8;  // 0 .. 524287 step 8
  const int row = i >> 7;
  float num[8] = {0.f, 0.f, 0.f, 0.f, 0.f, 0.f, 0.f, 0.f};
  float den = 0.f;
#pragma unroll
  for (int s = 0; s < 16; ++s) {
    bf16x8 v = *(const bf16x8*)(Op + (size_t)s * 524288 + i);
#pragma unroll
    for (int j = 0; j < 8; ++j) num[j] += (float)v[j];
    den += lp[(size_t)s * 4096 + row];
  }
  float inv = 1.f / den;
  float4 r0 = {num[0] * inv, num[1] * inv, num[2] * inv, num[3] * inv};
  float4 r1 = {num[4] * inv, num[5] * inv, num[6] * inv, num[7] * inv};
  *(float4*)(out + i) = r0;
  *(float4*)(out + i + 4) = r1;
}

extern "C" void kernel_launch(void* const* d_in, const int* in_sizes, int n_in,
                              void* d_out, int out_size, void* d_ws, size_t ws_size,
                              hipStream_t stream) {
  (void)in_sizes; (void)n_in; (void)out_size; (void)ws_size;
  const float* ctx      = (const float*)d_in[0];  // [4096,1024]
  const float* ent_embs = (const float*)d_in[1];  // [24636,128]
  const float* W1       = (const float*)d_in[2];  // [768,1024]
  const float* W2       = (const float*)d_in[3];  // [512,768]
  const float* W3       = (const float*)d_in[4];  // [128,512]
  const int*   ent_list = (const int*)d_in[5];    // [4096,50]
  float* out = (float*)d_out;

  // ws layout; peak use ~31 MB (ws is 256 MB).
  char* base = (char*)d_ws;
  __bf16* user_n = (__bf16*)(base);                       // 1 MB
  __bf16* user_t = (__bf16*)(base + (1ull << 20));        // 1 MB
  __bf16* qb     = (__bf16*)(base + (2ull << 20));        // 1 MB
  float*  lp     = (float*)(base + (3ull << 20));         // 256 KB [16][4096]
  f8_t*   ctxb   = (f8_t*)(base + (4ull << 20));          // 4 MB
  f8_t*   W1b    = (f8_t*)(base + (8ull << 20));          // 0.75 MB
  f8_t*   W2b    = (f8_t*)(base + 9175040ull);            // 8.75 MB, 384 KB
  f8_t*   W3b    = (f8_t*)(base + 9568256ull);            // 9.125 MB, 64 KB
  f8_t*   x1b    = (f8_t*)(base + (10ull << 20));         // 3 MB
  f8_t*   x2b    = (f8_t*)(base + (13ull << 20));         // 2 MB
  __bf16* O_part = (__bf16*)(base + (15ull << 20));       // 16 MB (bf16 x 16)

  // 6 dispatches.
  prep_kernel<<<3680, 256, 0, stream>>>(ctx, ctxb, W1, W1b, W2, W2b, W3, W3b,
                                        ent_embs, ent_list, user_n);
  gemm1_tr<<<640, 256, 0, stream>>>(ctxb, W1b, x1b, user_n, user_t);
  gemm_f8<2, 2, 2, 2, 1, false><<<dim3(8, 64), 256, 0, stream>>>(
      x1b, W2b, x2b, 4096, 512, 768);
  gemm_f8<2, 2, 1, 1, 0, true><<<dim3(4, 128), 256, 0, stream>>>(
      x2b, W3b, qb, 4096, 128, 512);
  flash_attn<<<dim3(32, 16), 256, 0, stream>>>(qb, user_n, user_t, O_part, lp);
  combine_kernel<<<256, 256, 0, stream>>>(O_part, lp, out);
}